// Round 10
// baseline (218.416 us; speedup 1.0000x reference)
//
#include <hip/hip_runtime.h>
#include <hip/hip_fp16.h>

#define N_NODES 50000
#define N_EDGES 800000
#define IN_DIM 128
#define HID_DIM 64
#define OUT_DIM 64
#define NUM_GRAPHS 512
#define CAP 64        // bucket capacity; deg ~ Poisson(16), P(deg>64) ~ 1e-15
#define NPART 8       // node partitions, one per XCD (heuristic pin)
#define PART_SZ 6250  // 50000 / 8

// ---- hybrid: blockIdx%9==8 -> layer-1 GEMM (unscaled fp16 out)
//              else          -> partitioned one-pass holey-CSR fill ---------
// fill partition p = blockIdx%8 (XCD-pinned under round-robin dispatch),
// chunk = blockIdx/9 (collision-free: the would-be duplicate block indices
// are exactly the %9==8 GEMM blocks). Each partition scans all edges but
// writes only dst in [p*6250,(p+1)*6250) -> its 1.6MB bucket window stays
// in one XCD's L2 -> scattered writes combine instead of bouncing lines.
__global__ __launch_bounds__(256) void gemm1_fill_kernel(
    const float* __restrict__ X, const float* __restrict__ W,
    const float* __restrict__ bias, __half* __restrict__ Yh, int n_nodes,
    const int* __restrict__ src, const int* __restrict__ dst,
    int* __restrict__ cursor, int* __restrict__ ssorted, int n_edges) {
    __shared__ float xs[16][IN_DIM];
    const int tid = threadIdx.x;

    if (blockIdx.x % 9 != 8) {  // ---- fill role ----
        const int p = blockIdx.x & 7;
        const int chunk = blockIdx.x / 9;
        int e = chunk * 256 + tid;
        if (e < n_edges) {
            int d = dst[e];
            int s = src[e];
            if (d / PART_SZ == p) {
                int pos = atomicAdd(&cursor[d], 1);
                if (pos < CAP) ssorted[(size_t)d * CAP + pos] = s;
            }
        }
        return;
    }

    // ---- GEMM role: Yh[n] = (fp16)(X[n] @ W1 + b1)  (dinv applied later) --
    const int idx = blockIdx.x / 9;
    const int base = idx * 16;
    const int nvec = 16 * IN_DIM / 4;
    const float4* X4 = reinterpret_cast<const float4*>(X + (size_t)base * IN_DIM);
    float4* xs4 = reinterpret_cast<float4*>(&xs[0][0]);
    for (int i = tid; i < nvec; i += 256) {
        int row = (i * 4) / IN_DIM;
        xs4[i] = (base + row < n_nodes) ? X4[i] : make_float4(0.f, 0.f, 0.f, 0.f);
    }
    __syncthreads();

    const int j = tid & 63;
    const int q = tid >> 6;
    float b = bias[j];
    float a0 = b, a1 = b, a2 = b, a3 = b;
#pragma unroll 4
    for (int k = 0; k < IN_DIM; ++k) {
        float w = W[k * 64 + j];  // coalesced wave load, L1-resident (32KB)
        a0 += w * xs[q * 4 + 0][k];
        a1 += w * xs[q * 4 + 1][k];
        a2 += w * xs[q * 4 + 2][k];
        a3 += w * xs[q * 4 + 3][k];
    }
    int n0 = base + q * 4;
    if (n0 + 0 < n_nodes) Yh[(size_t)(n0 + 0) * 64 + j] = __float2half(a0);
    if (n0 + 1 < n_nodes) Yh[(size_t)(n0 + 1) * 64 + j] = __float2half(a1);
    if (n0 + 2 < n_nodes) Yh[(size_t)(n0 + 2) * 64 + j] = __float2half(a2);
    if (n0 + 3 < n_nodes) Yh[(size_t)(n0 + 3) * 64 + j] = __float2half(a3);
}

// ---- scale + dinv + graph bounds ------------------------------------------
__global__ __launch_bounds__(256) void scale_bounds_kernel(
    __half* __restrict__ H1h, const int* __restrict__ deg,
    float* __restrict__ dinv, int n_nodes,
    const int* __restrict__ batch, int* __restrict__ gstart, int n_graphs) {
    const int tid = threadIdx.x;
    if (blockIdx.x == gridDim.x - 1) {  // ---- bounds role ----
        for (int g = tid; g <= n_graphs; g += 256) {
            int lo = 0, hi = n_nodes;
            while (lo < hi) {
                int mid = (lo + hi) >> 1;
                if (batch[mid] < g) lo = mid + 1; else hi = mid;
            }
            gstart[g] = lo;
        }
        return;
    }
    // ---- scale role: 512 half2 = 16 rows per block ----
    __half2* H2 = reinterpret_cast<__half2*>(H1h);
    const size_t base2 = (size_t)blockIdx.x * 512;
#pragma unroll
    for (int k = 0; k < 2; ++k) {
        size_t el = base2 + (size_t)k * 256 + tid;  // half2 index
        int row = (int)(el >> 5);
        if (row < n_nodes) {
            float dv = rsqrtf(fmaxf((float)deg[row], 1.0f));
            float2 f = __half22float2(H2[el]);
            H2[el] = __floats2half2_rn(f.x * dv, f.y * dv);
            if ((el & 31) == 0) dinv[row] = dv;
        }
    }
}

// ---- fused agg(layer1) + gemm(layer2): 16 dst rows per block -------------
__global__ __launch_bounds__(256) void agg_gemm_kernel(
    const __half* __restrict__ H, const int* __restrict__ ssorted,
    const int* __restrict__ deg, const float* __restrict__ dinv,
    const float* __restrict__ W, const float* __restrict__ bias,
    __half* __restrict__ Yh, int n_nodes) {
    __shared__ float xs[16][64];
    const int tid = threadIdx.x;
    const int lane = tid & 63;
    const int w = tid >> 6;
    const int lp = lane & 31;   // dim pair: dims 2lp, 2lp+1
    const int h = lane >> 5;    // node of the pair
    const int base = blockIdx.x * 16;
    const __half2* H2 = reinterpret_cast<const __half2*>(H);

#pragma unroll
    for (int p = 0; p < 2; ++p) {
        int row = 2 * (w + 4 * p) + h;  // 0..15
        int node = base + row;
        float2 a0 = make_float2(0.f, 0.f), a1 = make_float2(0.f, 0.f);
        if (node < n_nodes) {
            int beg = node * CAP;
            int end = beg + min(deg[node], CAP);
            int i = beg;
            for (; i + 1 < end; i += 2) {
                float2 f0 = __half22float2(H2[(size_t)ssorted[i] * 32 + lp]);
                float2 f1 = __half22float2(H2[(size_t)ssorted[i + 1] * 32 + lp]);
                a0.x += f0.x; a0.y += f0.y;
                a1.x += f1.x; a1.y += f1.y;
            }
            if (i < end) {
                float2 f = __half22float2(H2[(size_t)ssorted[i] * 32 + lp]);
                a0.x += f.x; a0.y += f.y;
            }
            float dv = dinv[node];
            *reinterpret_cast<float2*>(&xs[row][2 * lp]) =
                make_float2(fmaxf((a0.x + a1.x) * dv, 0.f),
                            fmaxf((a0.y + a1.y) * dv, 0.f));
        } else {
            *reinterpret_cast<float2*>(&xs[row][2 * lp]) = make_float2(0.f, 0.f);
        }
    }
    __syncthreads();

    float b = bias[lane];
    float c0 = b, c1 = b, c2 = b, c3 = b;
#pragma unroll 4
    for (int k = 0; k < 64; ++k) {
        float wv = W[k * 64 + lane];
        c0 += wv * xs[w * 4 + 0][k];
        c1 += wv * xs[w * 4 + 1][k];
        c2 += wv * xs[w * 4 + 2][k];
        c3 += wv * xs[w * 4 + 3][k];
    }
    int n0 = base + w * 4;
    if (n0 + 0 < n_nodes) Yh[(size_t)(n0 + 0) * 64 + lane] = __float2half(c0 * dinv[n0 + 0]);
    if (n0 + 1 < n_nodes) Yh[(size_t)(n0 + 1) * 64 + lane] = __float2half(c1 * dinv[n0 + 1]);
    if (n0 + 2 < n_nodes) Yh[(size_t)(n0 + 2) * 64 + lane] = __float2half(c2 * dinv[n0 + 2]);
    if (n0 + 3 < n_nodes) Yh[(size_t)(n0 + 3) * 64 + lane] = __float2half(c3 * dinv[n0 + 3]);
}

// ---- fused layer-2 agg + pool: 4 blocks per graph, dual-node half2 gather -
__global__ __launch_bounds__(256) void agg2_pool_kernel(
    const __half* __restrict__ H, const int* __restrict__ ssorted,
    const int* __restrict__ deg, const float* __restrict__ dinv,
    const int* __restrict__ gstart, float* __restrict__ out) {
    __shared__ float part[8][64];
    const int g = blockIdx.x >> 2;
    const int sub = blockIdx.x & 3;
    const int lane = threadIdx.x & 63;
    const int w = threadIdx.x >> 6;
    const int lp = lane & 31;
    const int h = lane >> 5;
    const __half2* H2 = reinterpret_cast<const __half2*>(H);
    const int beg = gstart[g], end = gstart[g + 1];

    float2 psum = make_float2(0.f, 0.f);
    for (int p = beg + 2 * (sub * 4 + w); p < end; p += 32) {
        int node = p + h;
        if (node < end) {
            int eb = node * CAP;
            int ee = eb + min(deg[node], CAP);
            float2 a0 = make_float2(0.f, 0.f), a1 = make_float2(0.f, 0.f);
            int i = eb;
            for (; i + 1 < ee; i += 2) {
                float2 f0 = __half22float2(H2[(size_t)ssorted[i] * 32 + lp]);
                float2 f1 = __half22float2(H2[(size_t)ssorted[i + 1] * 32 + lp]);
                a0.x += f0.x; a0.y += f0.y;
                a1.x += f1.x; a1.y += f1.y;
            }
            if (i < ee) {
                float2 f = __half22float2(H2[(size_t)ssorted[i] * 32 + lp]);
                a0.x += f.x; a0.y += f.y;
            }
            float dv = dinv[node];
            psum.x += fmaxf((a0.x + a1.x) * dv, 0.f);
            psum.y += fmaxf((a0.y + a1.y) * dv, 0.f);
        }
    }
    *reinterpret_cast<float2*>(&part[w * 2 + h][2 * lp]) = psum;
    __syncthreads();
    if (threadIdx.x < 64) {
        float s = 0.f;
#pragma unroll
        for (int r = 0; r < 8; ++r) s += part[r][threadIdx.x];
        atomicAdd(&out[(size_t)g * 64 + threadIdx.x], s);
    }
}

// ---- out /= count (from gstart) ------------------------------------------
__global__ void div_kernel(float* __restrict__ out, const int* __restrict__ gstart,
                           int n) {
    int t = blockIdx.x * blockDim.x + threadIdx.x;
    if (t < n) {
        int g = t >> 6;
        out[t] /= fmaxf((float)(gstart[g + 1] - gstart[g]), 1.0f);
    }
}

extern "C" void kernel_launch(void* const* d_in, const int* in_sizes, int n_in,
                              void* d_out, int out_size, void* d_ws, size_t ws_size,
                              hipStream_t stream) {
    const float* x     = (const float*)d_in[0];
    const int*   ei    = (const int*)d_in[1];   // [2, E]
    const int*   batch = (const int*)d_in[2];
    const float* W1    = (const float*)d_in[3];
    const float* b1    = (const float*)d_in[4];
    const float* W2    = (const float*)d_in[5];
    const float* b2    = (const float*)d_in[6];
    float* out = (float*)d_out;

    const int* srcp = ei;
    const int* dstp = ei + N_EDGES;

    // workspace layout (~26.2 MB)
    __half* H1h     = (__half*)d_ws;                        // 50000*64 fp16
    __half* H2h     = H1h + (size_t)N_NODES * 64;           // 50000*64 fp16
    float*  dinv    = (float*)(H2h + (size_t)N_NODES * 64); // 50000
    int*    cursor  = (int*)(dinv + N_NODES);               // 50000 (= deg)
    int*    ssorted = cursor + N_NODES;                     // 50000*CAP (holey)
    int*    gstart  = ssorted + (size_t)N_NODES * CAP;      // 513

    hipMemsetAsync(cursor, 0, N_NODES * sizeof(int), stream);
    hipMemsetAsync(out, 0, (size_t)NUM_GRAPHS * OUT_DIM * sizeof(float), stream);

    // hybrid: layer-1 GEMM || XCD-partitioned one-pass holey-CSR fill
    // grid 28128 = 3125 GEMM blocks (%9==8) + 8x3125 fill blocks (p=%8)
    gemm1_fill_kernel<<<28128, 256, 0, stream>>>(
        x, W1, b1, H1h, N_NODES, srcp, dstp, cursor, ssorted, N_EDGES);

    // H1h *= dinv (computed inline from deg) + gstart bounds
    scale_bounds_kernel<<<(N_NODES + 15) / 16 + 1, 256, 0, stream>>>(
        H1h, cursor, dinv, N_NODES, batch, gstart, NUM_GRAPHS);

    // fused layer-1 aggregation + layer-2 GEMM (dual-node half2 gather)
    agg_gemm_kernel<<<(N_NODES + 15) / 16, 256, 0, stream>>>(
        H1h, ssorted, cursor, dinv, W2, b2, H2h, N_NODES);

    // fused layer-2 aggregation + mean pool (4 blocks/graph, atomic combine)
    agg2_pool_kernel<<<4 * NUM_GRAPHS, 256, 0, stream>>>(
        H2h, ssorted, cursor, dinv, gstart, out);
    div_kernel<<<(NUM_GRAPHS * OUT_DIM + 255) / 256, 256, 0, stream>>>(
        out, gstart, NUM_GRAPHS * OUT_DIM);
}

// Round 11
// 194.373 us; speedup vs baseline: 1.1237x; 1.1237x over previous
//
#include <hip/hip_runtime.h>
#include <hip/hip_fp16.h>

#define N_NODES 50000
#define N_EDGES 800000
#define IN_DIM 128
#define HID_DIM 64
#define OUT_DIM 64
#define NUM_GRAPHS 512
#define CAP 64  // bucket capacity; deg ~ Poisson(16), P(deg>64) ~ 1e-15

// ---- hybrid: even blocks = layer-1 GEMM (unscaled fp16 out),
//              odd blocks  = one-pass holey-CSR fill (R9 form) --------------
__global__ __launch_bounds__(256) void gemm1_fill_kernel(
    const float* __restrict__ X, const float* __restrict__ W,
    const float* __restrict__ bias, __half* __restrict__ Yh, int n_nodes,
    const int* __restrict__ src, const int* __restrict__ dst,
    int* __restrict__ cursor, int* __restrict__ ssorted, int n_edges) {
    __shared__ float xs[16][IN_DIM];
    const int tid = threadIdx.x;
    const int idx = blockIdx.x >> 1;

    if (blockIdx.x & 1) {  // ---- fill role ----
        int e = idx * 256 + tid;
        if (e < n_edges) {
            int d = dst[e];
            int pos = atomicAdd(&cursor[d], 1);
            if (pos < CAP) ssorted[(size_t)d * CAP + pos] = src[e];
        }
        return;
    }

    // ---- GEMM role: Yh[n] = (fp16)(X[n] @ W1 + b1)  (dinv applied later) --
    const int base = idx * 16;
    const int nvec = 16 * IN_DIM / 4;
    const float4* X4 = reinterpret_cast<const float4*>(X + (size_t)base * IN_DIM);
    float4* xs4 = reinterpret_cast<float4*>(&xs[0][0]);
    for (int i = tid; i < nvec; i += 256) {
        int row = (i * 4) / IN_DIM;
        xs4[i] = (base + row < n_nodes) ? X4[i] : make_float4(0.f, 0.f, 0.f, 0.f);
    }
    __syncthreads();

    const int j = tid & 63;
    const int q = tid >> 6;
    float b = bias[j];
    float a0 = b, a1 = b, a2 = b, a3 = b;
#pragma unroll 4
    for (int k = 0; k < IN_DIM; ++k) {
        float w = W[k * 64 + j];  // coalesced wave load, L1-resident (32KB)
        a0 += w * xs[q * 4 + 0][k];
        a1 += w * xs[q * 4 + 1][k];
        a2 += w * xs[q * 4 + 2][k];
        a3 += w * xs[q * 4 + 3][k];
    }
    int n0 = base + q * 4;
    if (n0 + 0 < n_nodes) Yh[(size_t)(n0 + 0) * 64 + j] = __float2half(a0);
    if (n0 + 1 < n_nodes) Yh[(size_t)(n0 + 1) * 64 + j] = __float2half(a1);
    if (n0 + 2 < n_nodes) Yh[(size_t)(n0 + 2) * 64 + j] = __float2half(a2);
    if (n0 + 3 < n_nodes) Yh[(size_t)(n0 + 3) * 64 + j] = __float2half(a3);
}

// ---- scale + dinv + graph bounds ------------------------------------------
__global__ __launch_bounds__(256) void scale_bounds_kernel(
    __half* __restrict__ H1h, const int* __restrict__ deg,
    float* __restrict__ dinv, int n_nodes,
    const int* __restrict__ batch, int* __restrict__ gstart, int n_graphs) {
    const int tid = threadIdx.x;
    if (blockIdx.x == gridDim.x - 1) {  // ---- bounds role ----
        for (int g = tid; g <= n_graphs; g += 256) {
            int lo = 0, hi = n_nodes;
            while (lo < hi) {
                int mid = (lo + hi) >> 1;
                if (batch[mid] < g) lo = mid + 1; else hi = mid;
            }
            gstart[g] = lo;
        }
        return;
    }
    // ---- scale role: 512 half2 = 16 rows per block ----
    __half2* H2 = reinterpret_cast<__half2*>(H1h);
    const size_t base2 = (size_t)blockIdx.x * 512;
#pragma unroll
    for (int k = 0; k < 2; ++k) {
        size_t el = base2 + (size_t)k * 256 + tid;  // half2 index
        int row = (int)(el >> 5);
        if (row < n_nodes) {
            float dv = rsqrtf(fmaxf((float)deg[row], 1.0f));
            float2 f = __half22float2(H2[el]);
            H2[el] = __floats2half2_rn(f.x * dv, f.y * dv);
            if ((el & 31) == 0) dinv[row] = dv;
        }
    }
}

// ---- fused agg(layer1) + gemm(layer2): 16 dst rows per block -------------
// gather: int4 index loads (bucket 16B-aligned) + 4 H-rows in flight.
__global__ __launch_bounds__(256) void agg_gemm_kernel(
    const __half* __restrict__ H, const int* __restrict__ ssorted,
    const int* __restrict__ deg, const float* __restrict__ dinv,
    const float* __restrict__ W, const float* __restrict__ bias,
    __half* __restrict__ Yh, int n_nodes) {
    __shared__ float xs[16][64];
    const int tid = threadIdx.x;
    const int lane = tid & 63;
    const int w = tid >> 6;
    const int lp = lane & 31;   // dim pair: dims 2lp, 2lp+1
    const int h = lane >> 5;    // node of the pair
    const int base = blockIdx.x * 16;
    const __half2* H2 = reinterpret_cast<const __half2*>(H);

#pragma unroll
    for (int p = 0; p < 2; ++p) {
        int row = 2 * (w + 4 * p) + h;  // 0..15
        int node = base + row;
        float2 a0 = make_float2(0.f, 0.f), a1 = make_float2(0.f, 0.f);
        float2 a2 = make_float2(0.f, 0.f), a3 = make_float2(0.f, 0.f);
        if (node < n_nodes) {
            int beg = node * CAP;
            int end = beg + min(deg[node], CAP);
            int i = beg;
            for (; i + 3 < end; i += 4) {  // 16B-aligned: beg%64==0, step 4
                int4 s4 = *reinterpret_cast<const int4*>(ssorted + i);
                float2 f0 = __half22float2(H2[(size_t)s4.x * 32 + lp]);
                float2 f1 = __half22float2(H2[(size_t)s4.y * 32 + lp]);
                float2 f2 = __half22float2(H2[(size_t)s4.z * 32 + lp]);
                float2 f3 = __half22float2(H2[(size_t)s4.w * 32 + lp]);
                a0.x += f0.x; a0.y += f0.y;
                a1.x += f1.x; a1.y += f1.y;
                a2.x += f2.x; a2.y += f2.y;
                a3.x += f3.x; a3.y += f3.y;
            }
            for (; i < end; ++i) {
                float2 f = __half22float2(H2[(size_t)ssorted[i] * 32 + lp]);
                a0.x += f.x; a0.y += f.y;
            }
            float dv = dinv[node];
            *reinterpret_cast<float2*>(&xs[row][2 * lp]) =
                make_float2(fmaxf(((a0.x + a1.x) + (a2.x + a3.x)) * dv, 0.f),
                            fmaxf(((a0.y + a1.y) + (a2.y + a3.y)) * dv, 0.f));
        } else {
            *reinterpret_cast<float2*>(&xs[row][2 * lp]) = make_float2(0.f, 0.f);
        }
    }
    __syncthreads();

    float b = bias[lane];
    float c0 = b, c1 = b, c2 = b, c3 = b;
#pragma unroll 4
    for (int k = 0; k < 64; ++k) {
        float wv = W[k * 64 + lane];
        c0 += wv * xs[w * 4 + 0][k];
        c1 += wv * xs[w * 4 + 1][k];
        c2 += wv * xs[w * 4 + 2][k];
        c3 += wv * xs[w * 4 + 3][k];
    }
    int n0 = base + w * 4;
    if (n0 + 0 < n_nodes) Yh[(size_t)(n0 + 0) * 64 + lane] = __float2half(c0 * dinv[n0 + 0]);
    if (n0 + 1 < n_nodes) Yh[(size_t)(n0 + 1) * 64 + lane] = __float2half(c1 * dinv[n0 + 1]);
    if (n0 + 2 < n_nodes) Yh[(size_t)(n0 + 2) * 64 + lane] = __float2half(c2 * dinv[n0 + 2]);
    if (n0 + 3 < n_nodes) Yh[(size_t)(n0 + 3) * 64 + lane] = __float2half(c3 * dinv[n0 + 3]);
}

// ---- fused layer-2 agg + pool: 4 blocks per graph, same gather scheme ----
__global__ __launch_bounds__(256) void agg2_pool_kernel(
    const __half* __restrict__ H, const int* __restrict__ ssorted,
    const int* __restrict__ deg, const float* __restrict__ dinv,
    const int* __restrict__ gstart, float* __restrict__ out) {
    __shared__ float part[8][64];
    const int g = blockIdx.x >> 2;
    const int sub = blockIdx.x & 3;
    const int lane = threadIdx.x & 63;
    const int w = threadIdx.x >> 6;
    const int lp = lane & 31;
    const int h = lane >> 5;
    const __half2* H2 = reinterpret_cast<const __half2*>(H);
    const int beg = gstart[g], end = gstart[g + 1];

    float2 psum = make_float2(0.f, 0.f);
    for (int p = beg + 2 * (sub * 4 + w); p < end; p += 32) {
        int node = p + h;
        if (node < end) {
            int eb = node * CAP;
            int ee = eb + min(deg[node], CAP);
            float2 a0 = make_float2(0.f, 0.f), a1 = make_float2(0.f, 0.f);
            float2 a2 = make_float2(0.f, 0.f), a3 = make_float2(0.f, 0.f);
            int i = eb;
            for (; i + 3 < ee; i += 4) {
                int4 s4 = *reinterpret_cast<const int4*>(ssorted + i);
                float2 f0 = __half22float2(H2[(size_t)s4.x * 32 + lp]);
                float2 f1 = __half22float2(H2[(size_t)s4.y * 32 + lp]);
                float2 f2 = __half22float2(H2[(size_t)s4.z * 32 + lp]);
                float2 f3 = __half22float2(H2[(size_t)s4.w * 32 + lp]);
                a0.x += f0.x; a0.y += f0.y;
                a1.x += f1.x; a1.y += f1.y;
                a2.x += f2.x; a2.y += f2.y;
                a3.x += f3.x; a3.y += f3.y;
            }
            for (; i < ee; ++i) {
                float2 f = __half22float2(H2[(size_t)ssorted[i] * 32 + lp]);
                a0.x += f.x; a0.y += f.y;
            }
            float dv = dinv[node];
            psum.x += fmaxf(((a0.x + a1.x) + (a2.x + a3.x)) * dv, 0.f);
            psum.y += fmaxf(((a0.y + a1.y) + (a2.y + a3.y)) * dv, 0.f);
        }
    }
    *reinterpret_cast<float2*>(&part[w * 2 + h][2 * lp]) = psum;
    __syncthreads();
    if (threadIdx.x < 64) {
        float s = 0.f;
#pragma unroll
        for (int r = 0; r < 8; ++r) s += part[r][threadIdx.x];
        atomicAdd(&out[(size_t)g * 64 + threadIdx.x], s);
    }
}

// ---- out /= count (from gstart) ------------------------------------------
__global__ void div_kernel(float* __restrict__ out, const int* __restrict__ gstart,
                           int n) {
    int t = blockIdx.x * blockDim.x + threadIdx.x;
    if (t < n) {
        int g = t >> 6;
        out[t] /= fmaxf((float)(gstart[g + 1] - gstart[g]), 1.0f);
    }
}

extern "C" void kernel_launch(void* const* d_in, const int* in_sizes, int n_in,
                              void* d_out, int out_size, void* d_ws, size_t ws_size,
                              hipStream_t stream) {
    const float* x     = (const float*)d_in[0];
    const int*   ei    = (const int*)d_in[1];   // [2, E]
    const int*   batch = (const int*)d_in[2];
    const float* W1    = (const float*)d_in[3];
    const float* b1    = (const float*)d_in[4];
    const float* W2    = (const float*)d_in[5];
    const float* b2    = (const float*)d_in[6];
    float* out = (float*)d_out;

    const int* srcp = ei;
    const int* dstp = ei + N_EDGES;

    // workspace layout (~26.2 MB)
    __half* H1h     = (__half*)d_ws;                        // 50000*64 fp16
    __half* H2h     = H1h + (size_t)N_NODES * 64;           // 50000*64 fp16
    float*  dinv    = (float*)(H2h + (size_t)N_NODES * 64); // 50000
    int*    cursor  = (int*)(dinv + N_NODES);               // 50000 (= deg)
    int*    ssorted = cursor + N_NODES;                     // 50000*CAP (holey)
    int*    gstart  = ssorted + (size_t)N_NODES * CAP;      // 513

    hipMemsetAsync(cursor, 0, N_NODES * sizeof(int), stream);
    hipMemsetAsync(out, 0, (size_t)NUM_GRAPHS * OUT_DIM * sizeof(float), stream);

    // hybrid: layer-1 GEMM (unscaled fp16) || one-pass holey-CSR fill
    gemm1_fill_kernel<<<2 * ((N_NODES + 15) / 16), 256, 0, stream>>>(
        x, W1, b1, H1h, N_NODES, srcp, dstp, cursor, ssorted, N_EDGES);

    // H1h *= dinv (computed inline from deg) + gstart bounds
    scale_bounds_kernel<<<(N_NODES + 15) / 16 + 1, 256, 0, stream>>>(
        H1h, cursor, dinv, N_NODES, batch, gstart, NUM_GRAPHS);

    // fused layer-1 aggregation + layer-2 GEMM (int4 idx + 4-row gather)
    agg_gemm_kernel<<<(N_NODES + 15) / 16, 256, 0, stream>>>(
        H1h, ssorted, cursor, dinv, W2, b2, H2h, N_NODES);

    // fused layer-2 aggregation + mean pool (4 blocks/graph, atomic combine)
    agg2_pool_kernel<<<4 * NUM_GRAPHS, 256, 0, stream>>>(
        H2h, ssorted, cursor, dinv, gstart, out);
    div_kernel<<<(NUM_GRAPHS * OUT_DIM + 255) / 256, 256, 0, stream>>>(
        out, gstart, NUM_GRAPHS * OUT_DIM);
}

// Round 12
// 185.057 us; speedup vs baseline: 1.1803x; 1.0503x over previous
//
#include <hip/hip_runtime.h>
#include <hip/hip_fp16.h>

#define N_NODES 50000
#define N_EDGES 800000
#define IN_DIM 128
#define HID_DIM 64
#define OUT_DIM 64
#define NUM_GRAPHS 512
#define CAP 64  // bucket capacity; deg ~ Poisson(16), P(deg>64) ~ 1e-15

typedef unsigned short u16;

// ---- hybrid: even blocks = layer-1 GEMM (unscaled fp16 out),
//              odd blocks  = one-pass holey-CSR fill (u16 indices) ----------
__global__ __launch_bounds__(256) void gemm1_fill_kernel(
    const float* __restrict__ X, const float* __restrict__ W,
    const float* __restrict__ bias, __half* __restrict__ Yh, int n_nodes,
    const int* __restrict__ src, const int* __restrict__ dst,
    int* __restrict__ cursor, u16* __restrict__ ssorted, int n_edges) {
    __shared__ float xs[16][IN_DIM];
    const int tid = threadIdx.x;
    const int idx = blockIdx.x >> 1;

    if (blockIdx.x & 1) {  // ---- fill role ----
        int e = idx * 256 + tid;
        if (e < n_edges) {
            int d = dst[e];
            int pos = atomicAdd(&cursor[d], 1);
            if (pos < CAP) ssorted[(size_t)d * CAP + pos] = (u16)src[e];
        }
        return;
    }

    // ---- GEMM role: Yh[n] = (fp16)(X[n] @ W1 + b1)  (dinv applied later) --
    const int base = idx * 16;
    const int nvec = 16 * IN_DIM / 4;
    const float4* X4 = reinterpret_cast<const float4*>(X + (size_t)base * IN_DIM);
    float4* xs4 = reinterpret_cast<float4*>(&xs[0][0]);
    for (int i = tid; i < nvec; i += 256) {
        int row = (i * 4) / IN_DIM;
        xs4[i] = (base + row < n_nodes) ? X4[i] : make_float4(0.f, 0.f, 0.f, 0.f);
    }
    __syncthreads();

    const int j = tid & 63;
    const int q = tid >> 6;
    float b = bias[j];
    float a0 = b, a1 = b, a2 = b, a3 = b;
#pragma unroll 4
    for (int k = 0; k < IN_DIM; ++k) {
        float w = W[k * 64 + j];  // coalesced wave load, L1-resident (32KB)
        a0 += w * xs[q * 4 + 0][k];
        a1 += w * xs[q * 4 + 1][k];
        a2 += w * xs[q * 4 + 2][k];
        a3 += w * xs[q * 4 + 3][k];
    }
    int n0 = base + q * 4;
    if (n0 + 0 < n_nodes) Yh[(size_t)(n0 + 0) * 64 + j] = __float2half(a0);
    if (n0 + 1 < n_nodes) Yh[(size_t)(n0 + 1) * 64 + j] = __float2half(a1);
    if (n0 + 2 < n_nodes) Yh[(size_t)(n0 + 2) * 64 + j] = __float2half(a2);
    if (n0 + 3 < n_nodes) Yh[(size_t)(n0 + 3) * 64 + j] = __float2half(a3);
}

// ---- scale + dinv + graph bounds ------------------------------------------
__global__ __launch_bounds__(256) void scale_bounds_kernel(
    __half* __restrict__ H1h, const int* __restrict__ deg,
    float* __restrict__ dinv, int n_nodes,
    const int* __restrict__ batch, int* __restrict__ gstart, int n_graphs) {
    const int tid = threadIdx.x;
    if (blockIdx.x == gridDim.x - 1) {  // ---- bounds role ----
        for (int g = tid; g <= n_graphs; g += 256) {
            int lo = 0, hi = n_nodes;
            while (lo < hi) {
                int mid = (lo + hi) >> 1;
                if (batch[mid] < g) lo = mid + 1; else hi = mid;
            }
            gstart[g] = lo;
        }
        return;
    }
    // ---- scale role: 512 half2 = 16 rows per block ----
    __half2* H2 = reinterpret_cast<__half2*>(H1h);
    const size_t base2 = (size_t)blockIdx.x * 512;
#pragma unroll
    for (int k = 0; k < 2; ++k) {
        size_t el = base2 + (size_t)k * 256 + tid;  // half2 index
        int row = (int)(el >> 5);
        if (row < n_nodes) {
            float dv = rsqrtf(fmaxf((float)deg[row], 1.0f));
            float2 f = __half22float2(H2[el]);
            H2[el] = __floats2half2_rn(f.x * dv, f.y * dv);
            if ((el & 31) == 0) dinv[row] = dv;
        }
    }
}

// ---- 4-node/8B gather helper: lane covers dims [4*lq, 4*lq+4) of its node -
// acc held as two float2 (dims 4lq..4lq+1, 4lq+2..4lq+3).

// ---- fused agg(layer1) + gemm(layer2): 16 dst rows per block -------------
// slot = wave*4 + (lane>>4): 16 slots = 16 rows, one pass. 4-deep edge ILP.
__global__ __launch_bounds__(256) void agg_gemm_kernel(
    const __half* __restrict__ H, const u16* __restrict__ ssorted,
    const int* __restrict__ deg, const float* __restrict__ dinv,
    const float* __restrict__ W, const float* __restrict__ bias,
    __half* __restrict__ Yh, int n_nodes) {
    __shared__ float xs[16][64];
    const int tid = threadIdx.x;
    const int lane = tid & 63;
    const int w = tid >> 6;
    const int lq = lane & 15;            // dim quartet
    const int row = w * 4 + (lane >> 4); // 0..15
    const int base = blockIdx.x * 16;
    const uint2* H8 = reinterpret_cast<const uint2*>(H);  // 8B = 4 halves

    int node = base + row;
    float2 sA = make_float2(0.f, 0.f), sB = make_float2(0.f, 0.f);
    if (node < n_nodes) {
        int dg = min(deg[node], CAP);
        const u16* sp = ssorted + (size_t)node * CAP;
        int i = 0;
        for (; i + 3 < dg; i += 4) {  // 8B-aligned u16x4 index load
            ushort4 s4 = *reinterpret_cast<const ushort4*>(sp + i);
            uint2 v0 = H8[(size_t)s4.x * 16 + lq];
            uint2 v1 = H8[(size_t)s4.y * 16 + lq];
            uint2 v2 = H8[(size_t)s4.z * 16 + lq];
            uint2 v3 = H8[(size_t)s4.w * 16 + lq];
            float2 f;
            f = __half22float2(*reinterpret_cast<__half2*>(&v0.x)); sA.x += f.x; sA.y += f.y;
            f = __half22float2(*reinterpret_cast<__half2*>(&v0.y)); sB.x += f.x; sB.y += f.y;
            f = __half22float2(*reinterpret_cast<__half2*>(&v1.x)); sA.x += f.x; sA.y += f.y;
            f = __half22float2(*reinterpret_cast<__half2*>(&v1.y)); sB.x += f.x; sB.y += f.y;
            f = __half22float2(*reinterpret_cast<__half2*>(&v2.x)); sA.x += f.x; sA.y += f.y;
            f = __half22float2(*reinterpret_cast<__half2*>(&v2.y)); sB.x += f.x; sB.y += f.y;
            f = __half22float2(*reinterpret_cast<__half2*>(&v3.x)); sA.x += f.x; sA.y += f.y;
            f = __half22float2(*reinterpret_cast<__half2*>(&v3.y)); sB.x += f.x; sB.y += f.y;
        }
        for (; i < dg; ++i) {
            uint2 v = H8[(size_t)sp[i] * 16 + lq];
            float2 f;
            f = __half22float2(*reinterpret_cast<__half2*>(&v.x)); sA.x += f.x; sA.y += f.y;
            f = __half22float2(*reinterpret_cast<__half2*>(&v.y)); sB.x += f.x; sB.y += f.y;
        }
        float dv = dinv[node];
        *reinterpret_cast<float4*>(&xs[row][4 * lq]) =
            make_float4(fmaxf(sA.x * dv, 0.f), fmaxf(sA.y * dv, 0.f),
                        fmaxf(sB.x * dv, 0.f), fmaxf(sB.y * dv, 0.f));
    } else {
        *reinterpret_cast<float4*>(&xs[row][4 * lq]) = make_float4(0.f, 0.f, 0.f, 0.f);
    }
    __syncthreads();

    float b = bias[lane];
    float c0 = b, c1 = b, c2 = b, c3 = b;
#pragma unroll 4
    for (int k = 0; k < 64; ++k) {
        float wv = W[k * 64 + lane];
        c0 += wv * xs[w * 4 + 0][k];
        c1 += wv * xs[w * 4 + 1][k];
        c2 += wv * xs[w * 4 + 2][k];
        c3 += wv * xs[w * 4 + 3][k];
    }
    int n0 = base + w * 4;
    if (n0 + 0 < n_nodes) Yh[(size_t)(n0 + 0) * 64 + lane] = __float2half(c0 * dinv[n0 + 0]);
    if (n0 + 1 < n_nodes) Yh[(size_t)(n0 + 1) * 64 + lane] = __float2half(c1 * dinv[n0 + 1]);
    if (n0 + 2 < n_nodes) Yh[(size_t)(n0 + 2) * 64 + lane] = __float2half(c2 * dinv[n0 + 2]);
    if (n0 + 3 < n_nodes) Yh[(size_t)(n0 + 3) * 64 + lane] = __float2half(c3 * dinv[n0 + 3]);
}

// ---- fused layer-2 agg + pool: 4 blocks/graph, 4-node/8B gather ----------
__global__ __launch_bounds__(256) void agg2_pool_kernel(
    const __half* __restrict__ H, const u16* __restrict__ ssorted,
    const int* __restrict__ deg, const float* __restrict__ dinv,
    const int* __restrict__ gstart, float* __restrict__ out) {
    __shared__ float part[16][64];
    const int g = blockIdx.x >> 2;
    const int sbid = blockIdx.x & 3;
    const int tid = threadIdx.x;
    const int lane = tid & 63;
    const int w = tid >> 6;
    const int lq = lane & 15;
    const int slot = w * 4 + (lane >> 4);  // 0..15
    const uint2* H8 = reinterpret_cast<const uint2*>(H);
    const int beg = gstart[g], end = gstart[g + 1];

    float2 pA = make_float2(0.f, 0.f), pB = make_float2(0.f, 0.f);
    for (int node = beg + sbid * 16 + slot; node < end; node += 64) {
        int dg = min(deg[node], CAP);
        const u16* sp = ssorted + (size_t)node * CAP;
        float2 sA = make_float2(0.f, 0.f), sB = make_float2(0.f, 0.f);
        int i = 0;
        for (; i + 3 < dg; i += 4) {
            ushort4 s4 = *reinterpret_cast<const ushort4*>(sp + i);
            uint2 v0 = H8[(size_t)s4.x * 16 + lq];
            uint2 v1 = H8[(size_t)s4.y * 16 + lq];
            uint2 v2 = H8[(size_t)s4.z * 16 + lq];
            uint2 v3 = H8[(size_t)s4.w * 16 + lq];
            float2 f;
            f = __half22float2(*reinterpret_cast<__half2*>(&v0.x)); sA.x += f.x; sA.y += f.y;
            f = __half22float2(*reinterpret_cast<__half2*>(&v0.y)); sB.x += f.x; sB.y += f.y;
            f = __half22float2(*reinterpret_cast<__half2*>(&v1.x)); sA.x += f.x; sA.y += f.y;
            f = __half22float2(*reinterpret_cast<__half2*>(&v1.y)); sB.x += f.x; sB.y += f.y;
            f = __half22float2(*reinterpret_cast<__half2*>(&v2.x)); sA.x += f.x; sA.y += f.y;
            f = __half22float2(*reinterpret_cast<__half2*>(&v2.y)); sB.x += f.x; sB.y += f.y;
            f = __half22float2(*reinterpret_cast<__half2*>(&v3.x)); sA.x += f.x; sA.y += f.y;
            f = __half22float2(*reinterpret_cast<__half2*>(&v3.y)); sB.x += f.x; sB.y += f.y;
        }
        for (; i < dg; ++i) {
            uint2 v = H8[(size_t)sp[i] * 16 + lq];
            float2 f;
            f = __half22float2(*reinterpret_cast<__half2*>(&v.x)); sA.x += f.x; sA.y += f.y;
            f = __half22float2(*reinterpret_cast<__half2*>(&v.y)); sB.x += f.x; sB.y += f.y;
        }
        float dv = dinv[node];
        pA.x += fmaxf(sA.x * dv, 0.f); pA.y += fmaxf(sA.y * dv, 0.f);
        pB.x += fmaxf(sB.x * dv, 0.f); pB.y += fmaxf(sB.y * dv, 0.f);
    }
    *reinterpret_cast<float4*>(&part[slot][4 * lq]) =
        make_float4(pA.x, pA.y, pB.x, pB.y);
    __syncthreads();
    if (tid < 64) {
        float s = 0.f;
#pragma unroll
        for (int r = 0; r < 16; ++r) s += part[r][tid];
        atomicAdd(&out[(size_t)g * 64 + tid], s);
    }
}

// ---- out /= count (from gstart) ------------------------------------------
__global__ void div_kernel(float* __restrict__ out, const int* __restrict__ gstart,
                           int n) {
    int t = blockIdx.x * blockDim.x + threadIdx.x;
    if (t < n) {
        int g = t >> 6;
        out[t] /= fmaxf((float)(gstart[g + 1] - gstart[g]), 1.0f);
    }
}

extern "C" void kernel_launch(void* const* d_in, const int* in_sizes, int n_in,
                              void* d_out, int out_size, void* d_ws, size_t ws_size,
                              hipStream_t stream) {
    const float* x     = (const float*)d_in[0];
    const int*   ei    = (const int*)d_in[1];   // [2, E]
    const int*   batch = (const int*)d_in[2];
    const float* W1    = (const float*)d_in[3];
    const float* b1    = (const float*)d_in[4];
    const float* W2    = (const float*)d_in[5];
    const float* b2    = (const float*)d_in[6];
    float* out = (float*)d_out;

    const int* srcp = ei;
    const int* dstp = ei + N_EDGES;

    // workspace layout (~19.6 MB)
    __half* H1h     = (__half*)d_ws;                        // 50000*64 fp16
    __half* H2h     = H1h + (size_t)N_NODES * 64;           // 50000*64 fp16
    float*  dinv    = (float*)(H2h + (size_t)N_NODES * 64); // 50000
    int*    cursor  = (int*)(dinv + N_NODES);               // 50000 (= deg)
    u16*    ssorted = (u16*)(cursor + N_NODES);             // 50000*CAP u16
    int*    gstart  = (int*)(ssorted + (size_t)N_NODES * CAP);  // 513

    hipMemsetAsync(cursor, 0, N_NODES * sizeof(int), stream);
    hipMemsetAsync(out, 0, (size_t)NUM_GRAPHS * OUT_DIM * sizeof(float), stream);

    // hybrid: layer-1 GEMM (unscaled fp16) || one-pass holey-CSR fill (u16)
    gemm1_fill_kernel<<<2 * ((N_NODES + 15) / 16), 256, 0, stream>>>(
        x, W1, b1, H1h, N_NODES, srcp, dstp, cursor, ssorted, N_EDGES);

    // H1h *= dinv (computed inline from deg) + gstart bounds
    scale_bounds_kernel<<<(N_NODES + 15) / 16 + 1, 256, 0, stream>>>(
        H1h, cursor, dinv, N_NODES, batch, gstart, NUM_GRAPHS);

    // fused layer-1 aggregation + layer-2 GEMM (4-node/8B gather)
    agg_gemm_kernel<<<(N_NODES + 15) / 16, 256, 0, stream>>>(
        H1h, ssorted, cursor, dinv, W2, b2, H2h, N_NODES);

    // fused layer-2 aggregation + mean pool (4 blocks/graph, atomic combine)
    agg2_pool_kernel<<<4 * NUM_GRAPHS, 256, 0, stream>>>(
        H2h, ssorted, cursor, dinv, gstart, out);
    div_kernel<<<(NUM_GRAPHS * OUT_DIM + 255) / 256, 256, 0, stream>>>(
        out, gstart, NUM_GRAPHS * OUT_DIM);
}

// Round 13
// 181.726 us; speedup vs baseline: 1.2019x; 1.0183x over previous
//
#include <hip/hip_runtime.h>
#include <hip/hip_fp16.h>

#define N_NODES 50000
#define N_EDGES 800000
#define IN_DIM 128
#define HID_DIM 64
#define OUT_DIM 64
#define NUM_GRAPHS 512
#define CAP 64  // bucket capacity; deg ~ Poisson(16), P(deg>64) ~ 1e-15

typedef unsigned short u16;

// ---- hybrid: even blocks = layer-1 GEMM (unscaled fp16 out),
//              odd blocks  = one-pass holey-CSR fill (u16, nontemporal) -----
__global__ __launch_bounds__(256) void gemm1_fill_kernel(
    const float* __restrict__ X, const float* __restrict__ W,
    const float* __restrict__ bias, __half* __restrict__ Yh, int n_nodes,
    const int* __restrict__ src, const int* __restrict__ dst,
    int* __restrict__ cursor, u16* __restrict__ ssorted, int n_edges) {
    __shared__ float xs[16][IN_DIM];
    const int tid = threadIdx.x;
    const int idx = blockIdx.x >> 1;

    if (blockIdx.x & 1) {  // ---- fill role ----
        int e = idx * 256 + tid;
        if (e < n_edges) {
            int d = dst[e];
            int pos = atomicAdd(&cursor[d], 1);
            // nt store: bypass per-XCD L2 so line-merging happens at the
            // coherent LLC instead of bouncing dirty lines between XCDs.
            if (pos < CAP)
                __builtin_nontemporal_store((u16)src[e],
                                            &ssorted[(size_t)d * CAP + pos]);
        }
        return;
    }

    // ---- GEMM role: Yh[n] = (fp16)(X[n] @ W1 + b1)  (dinv applied later) --
    const int base = idx * 16;
    const int nvec = 16 * IN_DIM / 4;
    const float4* X4 = reinterpret_cast<const float4*>(X + (size_t)base * IN_DIM);
    float4* xs4 = reinterpret_cast<float4*>(&xs[0][0]);
    for (int i = tid; i < nvec; i += 256) {
        int row = (i * 4) / IN_DIM;
        xs4[i] = (base + row < n_nodes) ? X4[i] : make_float4(0.f, 0.f, 0.f, 0.f);
    }
    __syncthreads();

    const int j = tid & 63;
    const int q = tid >> 6;
    float b = bias[j];
    float a0 = b, a1 = b, a2 = b, a3 = b;
#pragma unroll 4
    for (int k = 0; k < IN_DIM; ++k) {
        float w = W[k * 64 + j];  // coalesced wave load, L1-resident (32KB)
        a0 += w * xs[q * 4 + 0][k];
        a1 += w * xs[q * 4 + 1][k];
        a2 += w * xs[q * 4 + 2][k];
        a3 += w * xs[q * 4 + 3][k];
    }
    int n0 = base + q * 4;
    if (n0 + 0 < n_nodes) Yh[(size_t)(n0 + 0) * 64 + j] = __float2half(a0);
    if (n0 + 1 < n_nodes) Yh[(size_t)(n0 + 1) * 64 + j] = __float2half(a1);
    if (n0 + 2 < n_nodes) Yh[(size_t)(n0 + 2) * 64 + j] = __float2half(a2);
    if (n0 + 3 < n_nodes) Yh[(size_t)(n0 + 3) * 64 + j] = __float2half(a3);
}

// ---- scale + dinv + graph bounds ------------------------------------------
__global__ __launch_bounds__(256) void scale_bounds_kernel(
    __half* __restrict__ H1h, const int* __restrict__ deg,
    float* __restrict__ dinv, int n_nodes,
    const int* __restrict__ batch, int* __restrict__ gstart, int n_graphs) {
    const int tid = threadIdx.x;
    if (blockIdx.x == gridDim.x - 1) {  // ---- bounds role ----
        for (int g = tid; g <= n_graphs; g += 256) {
            int lo = 0, hi = n_nodes;
            while (lo < hi) {
                int mid = (lo + hi) >> 1;
                if (batch[mid] < g) lo = mid + 1; else hi = mid;
            }
            gstart[g] = lo;
        }
        return;
    }
    // ---- scale role: 512 half2 = 16 rows per block ----
    __half2* H2 = reinterpret_cast<__half2*>(H1h);
    const size_t base2 = (size_t)blockIdx.x * 512;
#pragma unroll
    for (int k = 0; k < 2; ++k) {
        size_t el = base2 + (size_t)k * 256 + tid;  // half2 index
        int row = (int)(el >> 5);
        if (row < n_nodes) {
            float dv = rsqrtf(fmaxf((float)deg[row], 1.0f));
            float2 f = __half22float2(H2[el]);
            H2[el] = __floats2half2_rn(f.x * dv, f.y * dv);
            if ((el & 31) == 0) dinv[row] = dv;
        }
    }
}

// ---- gather unpack: uint4 = 8 halves -> 4 float2 accumulated --------------
__device__ __forceinline__ void acc_row(const uint4& v, float2& aa, float2& ab,
                                        float2& ac, float2& ad) {
    const __half2* hp = reinterpret_cast<const __half2*>(&v);
    float2 f;
    f = __half22float2(hp[0]); aa.x += f.x; aa.y += f.y;
    f = __half22float2(hp[1]); ab.x += f.x; ab.y += f.y;
    f = __half22float2(hp[2]); ac.x += f.x; ac.y += f.y;
    f = __half22float2(hp[3]); ad.x += f.x; ad.y += f.y;
}

// ---- fused agg(layer1) + gemm(layer2): 32 dst rows per block -------------
// gather: 8 lanes/node x uint4 (16B), 8 nodes/wave, 4-deep edge ILP
// -> 32 rows in flight per wave. GEMM phase: 8 rows per wave.
__global__ __launch_bounds__(256) void agg_gemm_kernel(
    const __half* __restrict__ H, const u16* __restrict__ ssorted,
    const int* __restrict__ deg, const float* __restrict__ dinv,
    const float* __restrict__ W, const float* __restrict__ bias,
    __half* __restrict__ Yh, int n_nodes) {
    __shared__ float xs[32][64];
    const int tid = threadIdx.x;
    const int lane = tid & 63;
    const int w = tid >> 6;
    const int lo = lane & 7;             // dim octet: dims 8lo..8lo+7
    const int slot = w * 8 + (lane >> 3);  // 0..31
    const int base = blockIdx.x * 32;
    const uint4* H16 = reinterpret_cast<const uint4*>(H);  // 16B = 8 halves

    int node = base + slot;
    float2 aa = make_float2(0.f, 0.f), ab = make_float2(0.f, 0.f);
    float2 ac = make_float2(0.f, 0.f), ad = make_float2(0.f, 0.f);
    if (node < n_nodes) {
        int dg = min(deg[node], CAP);
        const u16* sp = ssorted + (size_t)node * CAP;
        int i = 0;
        for (; i + 3 < dg; i += 4) {
            ushort4 s4 = *reinterpret_cast<const ushort4*>(sp + i);
            uint4 v0 = H16[(size_t)s4.x * 8 + lo];
            uint4 v1 = H16[(size_t)s4.y * 8 + lo];
            uint4 v2 = H16[(size_t)s4.z * 8 + lo];
            uint4 v3 = H16[(size_t)s4.w * 8 + lo];
            acc_row(v0, aa, ab, ac, ad);
            acc_row(v1, aa, ab, ac, ad);
            acc_row(v2, aa, ab, ac, ad);
            acc_row(v3, aa, ab, ac, ad);
        }
        for (; i < dg; ++i) {
            uint4 v = H16[(size_t)sp[i] * 8 + lo];
            acc_row(v, aa, ab, ac, ad);
        }
        float dv = dinv[node];
        *reinterpret_cast<float4*>(&xs[slot][8 * lo]) =
            make_float4(fmaxf(aa.x * dv, 0.f), fmaxf(aa.y * dv, 0.f),
                        fmaxf(ab.x * dv, 0.f), fmaxf(ab.y * dv, 0.f));
        *reinterpret_cast<float4*>(&xs[slot][8 * lo + 4]) =
            make_float4(fmaxf(ac.x * dv, 0.f), fmaxf(ac.y * dv, 0.f),
                        fmaxf(ad.x * dv, 0.f), fmaxf(ad.y * dv, 0.f));
    } else {
        *reinterpret_cast<float4*>(&xs[slot][8 * lo]) = make_float4(0.f, 0.f, 0.f, 0.f);
        *reinterpret_cast<float4*>(&xs[slot][8 * lo + 4]) = make_float4(0.f, 0.f, 0.f, 0.f);
    }
    __syncthreads();

    float b = bias[lane];
    float c[8];
#pragma unroll
    for (int r = 0; r < 8; ++r) c[r] = b;
#pragma unroll 4
    for (int k = 0; k < 64; ++k) {
        float wv = W[k * 64 + lane];
#pragma unroll
        for (int r = 0; r < 8; ++r) c[r] += wv * xs[w * 8 + r][k];
    }
    int n0 = base + w * 8;
#pragma unroll
    for (int r = 0; r < 8; ++r)
        if (n0 + r < n_nodes)
            Yh[(size_t)(n0 + r) * 64 + lane] = __float2half(c[r] * dinv[n0 + r]);
}

// ---- fused layer-2 agg + pool: 2 blocks/graph, 32 node-slots/block -------
__global__ __launch_bounds__(256) void agg2_pool_kernel(
    const __half* __restrict__ H, const u16* __restrict__ ssorted,
    const int* __restrict__ deg, const float* __restrict__ dinv,
    const int* __restrict__ gstart, float* __restrict__ out) {
    __shared__ float part[32][64];
    const int g = blockIdx.x >> 1;
    const int sbid = blockIdx.x & 1;
    const int tid = threadIdx.x;
    const int lane = tid & 63;
    const int w = tid >> 6;
    const int lo = lane & 7;
    const int slot = w * 8 + (lane >> 3);  // 0..31
    const uint4* H16 = reinterpret_cast<const uint4*>(H);
    const int beg = gstart[g], end = gstart[g + 1];

    float2 pa = make_float2(0.f, 0.f), pb = make_float2(0.f, 0.f);
    float2 pc = make_float2(0.f, 0.f), pd = make_float2(0.f, 0.f);
    for (int node = beg + sbid * 32 + slot; node < end; node += 64) {
        int dg = min(deg[node], CAP);
        const u16* sp = ssorted + (size_t)node * CAP;
        float2 aa = make_float2(0.f, 0.f), ab = make_float2(0.f, 0.f);
        float2 ac = make_float2(0.f, 0.f), ad = make_float2(0.f, 0.f);
        int i = 0;
        for (; i + 3 < dg; i += 4) {
            ushort4 s4 = *reinterpret_cast<const ushort4*>(sp + i);
            uint4 v0 = H16[(size_t)s4.x * 8 + lo];
            uint4 v1 = H16[(size_t)s4.y * 8 + lo];
            uint4 v2 = H16[(size_t)s4.z * 8 + lo];
            uint4 v3 = H16[(size_t)s4.w * 8 + lo];
            acc_row(v0, aa, ab, ac, ad);
            acc_row(v1, aa, ab, ac, ad);
            acc_row(v2, aa, ab, ac, ad);
            acc_row(v3, aa, ab, ac, ad);
        }
        for (; i < dg; ++i) {
            uint4 v = H16[(size_t)sp[i] * 8 + lo];
            acc_row(v, aa, ab, ac, ad);
        }
        float dv = dinv[node];
        pa.x += fmaxf(aa.x * dv, 0.f); pa.y += fmaxf(aa.y * dv, 0.f);
        pb.x += fmaxf(ab.x * dv, 0.f); pb.y += fmaxf(ab.y * dv, 0.f);
        pc.x += fmaxf(ac.x * dv, 0.f); pc.y += fmaxf(ac.y * dv, 0.f);
        pd.x += fmaxf(ad.x * dv, 0.f); pd.y += fmaxf(ad.y * dv, 0.f);
    }
    *reinterpret_cast<float4*>(&part[slot][8 * lo]) = make_float4(pa.x, pa.y, pb.x, pb.y);
    *reinterpret_cast<float4*>(&part[slot][8 * lo + 4]) = make_float4(pc.x, pc.y, pd.x, pd.y);
    __syncthreads();
    if (tid < 64) {
        float s = 0.f;
#pragma unroll
        for (int r = 0; r < 32; ++r) s += part[r][tid];
        atomicAdd(&out[(size_t)g * 64 + tid], s);
    }
}

// ---- out /= count (from gstart) ------------------------------------------
__global__ void div_kernel(float* __restrict__ out, const int* __restrict__ gstart,
                           int n) {
    int t = blockIdx.x * blockDim.x + threadIdx.x;
    if (t < n) {
        int g = t >> 6;
        out[t] /= fmaxf((float)(gstart[g + 1] - gstart[g]), 1.0f);
    }
}

extern "C" void kernel_launch(void* const* d_in, const int* in_sizes, int n_in,
                              void* d_out, int out_size, void* d_ws, size_t ws_size,
                              hipStream_t stream) {
    const float* x     = (const float*)d_in[0];
    const int*   ei    = (const int*)d_in[1];   // [2, E]
    const int*   batch = (const int*)d_in[2];
    const float* W1    = (const float*)d_in[3];
    const float* b1    = (const float*)d_in[4];
    const float* W2    = (const float*)d_in[5];
    const float* b2    = (const float*)d_in[6];
    float* out = (float*)d_out;

    const int* srcp = ei;
    const int* dstp = ei + N_EDGES;

    // workspace layout (~19.6 MB)
    __half* H1h     = (__half*)d_ws;                        // 50000*64 fp16
    __half* H2h     = H1h + (size_t)N_NODES * 64;           // 50000*64 fp16
    float*  dinv    = (float*)(H2h + (size_t)N_NODES * 64); // 50000
    int*    cursor  = (int*)(dinv + N_NODES);               // 50000 (= deg)
    u16*    ssorted = (u16*)(cursor + N_NODES);             // 50000*CAP u16
    int*    gstart  = (int*)(ssorted + (size_t)N_NODES * CAP);  // 513

    hipMemsetAsync(cursor, 0, N_NODES * sizeof(int), stream);
    hipMemsetAsync(out, 0, (size_t)NUM_GRAPHS * OUT_DIM * sizeof(float), stream);

    // hybrid: layer-1 GEMM (unscaled fp16) || one-pass holey-CSR fill (u16 nt)
    gemm1_fill_kernel<<<2 * ((N_NODES + 15) / 16), 256, 0, stream>>>(
        x, W1, b1, H1h, N_NODES, srcp, dstp, cursor, ssorted, N_EDGES);

    // H1h *= dinv (computed inline from deg) + gstart bounds
    scale_bounds_kernel<<<(N_NODES + 15) / 16 + 1, 256, 0, stream>>>(
        H1h, cursor, dinv, N_NODES, batch, gstart, NUM_GRAPHS);

    // fused layer-1 aggregation + layer-2 GEMM (8-node/16B gather, 32-row tile)
    agg_gemm_kernel<<<(N_NODES + 31) / 32, 256, 0, stream>>>(
        H1h, ssorted, cursor, dinv, W2, b2, H2h, N_NODES);

    // fused layer-2 aggregation + mean pool (2 blocks/graph, atomic combine)
    agg2_pool_kernel<<<2 * NUM_GRAPHS, 256, 0, stream>>>(
        H2h, ssorted, cursor, dinv, gstart, out);
    div_kernel<<<(NUM_GRAPHS * OUT_DIM + 255) / 256, 256, 0, stream>>>(
        out, gstart, NUM_GRAPHS * OUT_DIM);
}